// Round 1
// baseline (234.300 us; speedup 1.0000x reference)
//
#include <hip/hip_runtime.h>
#include <hip/hip_bf16.h>
#include <cmath>

typedef _Float16 half8 __attribute__((ext_vector_type(8)));
typedef _Float16 half4 __attribute__((ext_vector_type(4)));
typedef float f32x4 __attribute__((ext_vector_type(4)));

// Problem geometry (fixed): B=4, S=4096, D=1024, D_H=1024
// M = B*S = 16384, K = D = 1024, N = 3*D_H = 3072
#define M_DIM 16384
#define K_DIM 1024
#define N_DIM 3072
#define S_LEN 4096
#define NCHUNK 64   // chunks per sequence
#define CLEN 64     // timesteps per chunk

__device__ __forceinline__ float sigmoid_f(float x) {
    return 1.0f / (1.0f + __expf(-x));
}

// ---------------- cast kernels ----------------
// x (fp32, 16M) -> f16, 4 elements/thread
__global__ void k_cast_x(const float* __restrict__ x, _Float16* __restrict__ xb) {
    int i = blockIdx.x * blockDim.x + threadIdx.x;
    float4 v = reinterpret_cast<const float4*>(x)[i];
    half4 h;
    h.x = (_Float16)v.x; h.y = (_Float16)v.y;
    h.z = (_Float16)v.z; h.w = (_Float16)v.w;
    reinterpret_cast<half4*>(xb)[i] = h;
}

// W (K=1024, N=3072) fp32 row-major -> Wt (N, K) f16
__global__ void k_cast_w(const float* __restrict__ W, _Float16* __restrict__ Wt) {
    int t = blockIdx.x * blockDim.x + threadIdx.x;   // 3145728 threads
    int n = t >> 10;
    int k = t & 1023;
    Wt[t] = (_Float16)W[(size_t)k * N_DIM + n];
}

// ---------------- GEMM + activation epilogue ----------------
// A: (16384,1024) f16 row-major. Bt: (3072,1024) f16 row-major (W^T).
// G: (16384,3072) f16 = act(A@W + bias); col<1024 -> tanh, else sigmoid.
__global__ __launch_bounds__(256, 2) void k_gemm(
    const _Float16* __restrict__ A,
    const _Float16* __restrict__ Bt,
    const float* __restrict__ bias,
    _Float16* __restrict__ G)
{
    __shared__ _Float16 As[128 * 64];
    __shared__ _Float16 Bs[128 * 64];

    const int lane = threadIdx.x & 63;
    const int w    = threadIdx.x >> 6;     // wave 0..3
    const int wr   = w >> 1;               // wave row (2x2 wave grid)
    const int wc   = w & 1;

    const int bid   = blockIdx.x;
    const int tileM = (bid / 24) * 128;
    const int tileN = (bid % 24) * 128;

    f32x4 acc[4][4] = {};

    const int rsub = lane >> 3;          // 0..7 : row within 8-row chunk
    const int ksub = (lane & 7) * 8;     // f16 element offset in k

    for (int kt = 0; kt < 16; ++kt) {
        __syncthreads();
        // Stage A-tile and B-tile into LDS: each wave stages 4 x 1KB chunks of each.
        // LDS dest is wave-uniform base + lane*16 (global src is per-lane).
        #pragma unroll
        for (int c = 0; c < 4; ++c) {
            const int row = w * 32 + c * 8 + rsub;
            const _Float16* gA = A  + (size_t)(tileM + row) * K_DIM + kt * 64 + ksub;
            const _Float16* gB = Bt + (size_t)(tileN + row) * K_DIM + kt * 64 + ksub;
            __builtin_amdgcn_global_load_lds(
                (const __attribute__((address_space(1))) void*)gA,
                (__attribute__((address_space(3))) void*)(As + (w * 32 + c * 8) * 64),
                16, 0, 0);
            __builtin_amdgcn_global_load_lds(
                (const __attribute__((address_space(1))) void*)gB,
                (__attribute__((address_space(3))) void*)(Bs + (w * 32 + c * 8) * 64),
                16, 0, 0);
        }
        __syncthreads();   // compiler drains vmcnt before barrier

        #pragma unroll
        for (int ks = 0; ks < 2; ++ks) {
            half8 af[4], bf[4];
            #pragma unroll
            for (int i = 0; i < 4; ++i)
                af[i] = *reinterpret_cast<const half8*>(
                    &As[(wr * 64 + i * 16 + (lane & 15)) * 64 + ks * 32 + (lane >> 4) * 8]);
            #pragma unroll
            for (int j = 0; j < 4; ++j)
                bf[j] = *reinterpret_cast<const half8*>(
                    &Bs[(wc * 64 + j * 16 + (lane & 15)) * 64 + ks * 32 + (lane >> 4) * 8]);
            #pragma unroll
            for (int i = 0; i < 4; ++i)
                #pragma unroll
                for (int j = 0; j < 4; ++j)
                    acc[i][j] = __builtin_amdgcn_mfma_f32_16x16x32_f16(
                        af[i], bf[j], acc[i][j], 0, 0, 0);
        }
    }

    // Epilogue: bias + activation, store f16.
    // C/D layout: col = lane&15, row = (lane>>4)*4 + reg.
    #pragma unroll
    for (int j = 0; j < 4; ++j) {
        const int n = tileN + wc * 64 + j * 16 + (lane & 15);
        const float bn = bias[n];
        const bool is_tanh = (n < 1024);
        #pragma unroll
        for (int i = 0; i < 4; ++i) {
            const int mbase = tileM + wr * 64 + i * 16 + (lane >> 4) * 4;
            #pragma unroll
            for (int r = 0; r < 4; ++r) {
                float v = acc[i][j][r] + bn;
                float o = is_tanh ? tanhf(v) : sigmoid_f(v);
                G[(size_t)(mbase + r) * N_DIM + n] = (_Float16)o;
            }
        }
    }
}

// ---------------- chunked scan ----------------
// Channel c = (b,d); per channel S=4096 steps split into 64 chunks of 64.
// Level 1: per (b,chunk,d): local scan -> summary (A_prod, H_local_end)
__global__ void k_scan1(const _Float16* __restrict__ G,
                        float* __restrict__ sumA, float* __restrict__ sumH) {
    const int gid   = blockIdx.x;          // 0..1023
    const int dblk  = gid & 3;
    const int chunk = (gid >> 2) & 63;
    const int b     = gid >> 8;
    const int d     = dblk * 256 + threadIdx.x;

    const _Float16* base = G + (size_t)(b * S_LEN + chunk * CLEN) * N_DIM;
    float A = 1.0f, H = 0.0f;
    #pragma unroll 4
    for (int s = 0; s < CLEN; ++s) {
        float g0 = (float)base[(size_t)s * N_DIM + d];           // tanh(p0)
        float g1 = (float)base[(size_t)s * N_DIM + 1024 + d];    // sigmoid(p1) = input gate
        float a  = 1.0f - g1;                                    // forget gate
        float kv = g0 * g1;
        H = fmaf(a, H, kv);
        A *= a;
    }
    const int cidx = (b * NCHUNK + chunk) * 1024 + d;
    sumA[cidx] = A;
    sumH[cidx] = H;
}

// Level 2: per channel, serial scan over 64 chunk summaries -> carry-in prefix h
__global__ void k_scan2(const float* __restrict__ sumA, const float* __restrict__ sumH,
                        float* __restrict__ pref) {
    const int c = blockIdx.x * blockDim.x + threadIdx.x;  // 0..4095
    const int b = c >> 10;
    const int d = c & 1023;
    float h = 0.0f;
    #pragma unroll 8
    for (int chunk = 0; chunk < NCHUNK; ++chunk) {
        const int idx = (b * NCHUNK + chunk) * 1024 + d;
        pref[idx] = h;
        h = fmaf(sumA[idx], h, sumH[idx]);
    }
}

// Level 3: re-scan chunk with carry-in h, write out = tanh(h) * output_gate
__global__ void k_scan3(const _Float16* __restrict__ G,
                        const float* __restrict__ pref,
                        float* __restrict__ out) {
    const int gid   = blockIdx.x;
    const int dblk  = gid & 3;
    const int chunk = (gid >> 2) & 63;
    const int b     = gid >> 8;
    const int d     = dblk * 256 + threadIdx.x;

    const _Float16* base = G + (size_t)(b * S_LEN + chunk * CLEN) * N_DIM;
    float h = pref[(b * NCHUNK + chunk) * 1024 + d];
    #pragma unroll 4
    for (int s = 0; s < CLEN; ++s) {
        float g0 = (float)base[(size_t)s * N_DIM + d];
        float g1 = (float)base[(size_t)s * N_DIM + 1024 + d];
        float g2 = (float)base[(size_t)s * N_DIM + 2048 + d];    // output gate
        float a  = 1.0f - g1;
        float kv = g0 * g1;
        h = fmaf(a, h, kv);
        out[(size_t)(b * S_LEN + chunk * CLEN + s) * 1024 + d] = tanhf(h) * g2;
    }
}

extern "C" void kernel_launch(void* const* d_in, const int* in_sizes, int n_in,
                              void* d_out, int out_size, void* d_ws, size_t ws_size,
                              hipStream_t stream) {
    const float* x = (const float*)d_in[0];   // (4,4096,1024)
    const float* W = (const float*)d_in[1];   // (1024,3072)
    const float* b = (const float*)d_in[2];   // (3072,)
    float* out = (float*)d_out;

    char* ws = (char*)d_ws;
    _Float16* xb = (_Float16*)ws;                               // 32 MB
    _Float16* Wt = (_Float16*)(ws + 33554432);                  // 6 MB
    _Float16* G  = (_Float16*)(ws + 33554432 + 6291456);        // 96 MB
    float* sumA  = (float*)(ws + 140509184);                    // 1 MB
    float* sumH  = sumA + 4096 * NCHUNK;                        // 1 MB
    float* pref  = sumH + 4096 * NCHUNK;                        // 1 MB

    k_cast_x<<<16384, 256, 0, stream>>>(x, xb);      // 16777216/4/256
    k_cast_w<<<12288, 256, 0, stream>>>(W, Wt);      // 3145728/256
    k_gemm <<<3072, 256, 0, stream>>>(xb, Wt, b, G); // (16384/128)*(3072/128)
    k_scan1<<<1024, 256, 0, stream>>>(G, sumA, sumH);
    k_scan2<<<16,   256, 0, stream>>>(sumA, sumH, pref);
    k_scan3<<<1024, 256, 0, stream>>>(G, pref, out);
    (void)in_sizes; (void)n_in; (void)out_size; (void)ws_size;
}

// Round 2
// 230.578 us; speedup vs baseline: 1.0161x; 1.0161x over previous
//
#include <hip/hip_runtime.h>
#include <hip/hip_bf16.h>
#include <cmath>

typedef _Float16 half8 __attribute__((ext_vector_type(8)));
typedef _Float16 half4 __attribute__((ext_vector_type(4)));
typedef float f32x4 __attribute__((ext_vector_type(4)));

// Geometry: B=4, S=4096, D=1024, D_H=1024 -> M=16384, K=1024, N=3072
#define M_DIM 16384
#define K_DIM 1024
#define N_DIM 3072
#define S_LEN 4096
#define NCHUNK 64
#define CLEN 64

// GEMM tiling
#define BM 256
#define BN 128
#define BK 64
#define NT 16              // K / BK
#define A_E 16384          // BM*BK f16 elems (32KB)
#define SLOT_E 24576       // (BM+BN)*BK f16 elems (48KB)

__device__ __forceinline__ float sigmoid_f(float x) {
    return 1.0f / (1.0f + __expf(-x));
}

// ---------------- cast kernels ----------------
__global__ void k_cast_x(const float* __restrict__ x, _Float16* __restrict__ xb) {
    int i = blockIdx.x * blockDim.x + threadIdx.x;
    float4 v = reinterpret_cast<const float4*>(x)[i];
    half4 h;
    h.x = (_Float16)v.x; h.y = (_Float16)v.y;
    h.z = (_Float16)v.z; h.w = (_Float16)v.w;
    reinterpret_cast<half4*>(xb)[i] = h;
}

// W (1024,3072) fp32 -> Wt (3072,1024) f16, LDS-tiled transpose (coalesced both sides)
__global__ void k_cast_w(const float* __restrict__ W, _Float16* __restrict__ Wt) {
    __shared__ float t[64][65];
    const int k0 = (blockIdx.x / 48) * 64;
    const int n0 = (blockIdx.x % 48) * 64;
    const int c  = threadIdx.x & 63;
    const int r0 = threadIdx.x >> 6;   // 0..3
    #pragma unroll
    for (int i = 0; i < 16; ++i) {
        int r = r0 + i * 4;
        t[r][c] = W[(size_t)(k0 + r) * N_DIM + n0 + c];
    }
    __syncthreads();
    #pragma unroll
    for (int i = 0; i < 16; ++i) {
        int r = r0 + i * 4;
        Wt[(size_t)(n0 + r) * K_DIM + k0 + c] = (_Float16)t[c][r];
    }
}

// ---------------- GEMM + activation epilogue ----------------
// A (16384,1024) f16 rm; Bt (3072,1024) f16 rm (=W^T); G = act(A@W+b) f16.
// 512 threads = 8 waves (4M x 2N), per-wave 64x64 output.
// 3-slot LDS ring, counted vmcnt(6), XOR-swizzled LDS (write via pre-swizzled
// global source since global_load_lds dest must stay linear).
__global__ __launch_bounds__(512, 2) void k_gemm(
    const _Float16* __restrict__ A,
    const _Float16* __restrict__ Bt,
    const float* __restrict__ bias,
    _Float16* __restrict__ G)
{
    extern __shared__ _Float16 lds[];   // 3 * SLOT_E f16 = 144KB

    const int tid  = threadIdx.x;
    const int lane = tid & 63;
    const int wid  = tid >> 6;     // 0..7
    const int wr   = wid >> 1;     // 0..3 (M)
    const int wc   = wid & 1;      // 0..1 (N)

    // XCD-aware swizzle: 1536 blocks, 1536 % 8 == 0 -> simple bijective form
    const int bid   = blockIdx.x;
    const int wg    = (bid & 7) * 192 + (bid >> 3);
    const int tileM = (wg / 24) * BM;
    const int tileN = (wg % 24) * BN;

    // Staging geometry: dest is linear; source column pre-swizzled.
    // dest row = c*64 + wid*8 + (lane>>3); row&7 == lane>>3 for all c.
    const int l3   = lane >> 3;
    const int c8   = lane & 7;
    const int scol = ((c8 ^ l3) << 3);          // swizzled source col (f16 elems)
    const _Float16* gA = A  + (size_t)(tileM + wid * 8 + l3) * K_DIM + scol;
    const _Float16* gB = Bt + (size_t)(tileN + wid * 8 + l3) * K_DIM + scol;

    // Fragment-read geometry: row&7 == lane&7 -> XOR term per-thread constant.
    const int l15 = lane & 15;
    const int hi  = lane >> 4;                  // 0..3
    const int swz = (l15 & 7) << 3;
    const int o0  = (hi * 8)      ^ swz;        // ks=0 col offset (elems)
    const int o1  = (32 + hi * 8) ^ swz;        // ks=1

    f32x4 acc[4][4] = {};

#define GL(SRC, DST) __builtin_amdgcn_global_load_lds( \
        (const __attribute__((address_space(1))) void*)(SRC), \
        (__attribute__((address_space(3))) void*)(DST), 16, 0, 0)

#define STAGE(kt, slot) do { \
        _Float16* as_ = lds + (slot) * SLOT_E + wid * 512; \
        _Float16* bs_ = lds + (slot) * SLOT_E + A_E + wid * 512; \
        const _Float16* ga_ = gA + (size_t)(kt) * BK; \
        const _Float16* gb_ = gB + (size_t)(kt) * BK; \
        GL(ga_,                        as_);          \
        GL(ga_ +  64 * K_DIM,          as_ + 4096);   \
        GL(ga_ + 128 * K_DIM,          as_ + 8192);   \
        GL(ga_ + 192 * K_DIM,          as_ + 12288);  \
        GL(gb_,                        bs_);          \
        GL(gb_ +  64 * K_DIM,          bs_ + 4096);   \
    } while (0)

    // Prologue: 2 tiles in flight; tile0 landed before first reads.
    STAGE(0, 0);
    STAGE(1, 1);
    asm volatile("s_waitcnt vmcnt(6)" ::: "memory");
    __builtin_amdgcn_s_barrier();

    int sC = 0, sS = 2;
    #pragma unroll 1
    for (int t = 0; t < NT; ++t) {
        if (t + 2 < NT) STAGE(t + 2, sS);   // lookahead-2 into freed slot

        const _Float16* as = lds + sC * SLOT_E + (wr * 64 + l15) * 64;
        const _Float16* bs = lds + sC * SLOT_E + A_E + (wc * 64 + l15) * 64;
        half8 a0[4], a1[4], b0[4], b1[4];
        #pragma unroll
        for (int i = 0; i < 4; ++i) {
            a0[i] = *(const half8*)(as + i * 1024 + o0);
            a1[i] = *(const half8*)(as + i * 1024 + o1);
            b0[i] = *(const half8*)(bs + i * 1024 + o0);
            b1[i] = *(const half8*)(bs + i * 1024 + o1);
        }

        __builtin_amdgcn_s_setprio(1);
        #pragma unroll
        for (int i = 0; i < 4; ++i)
            #pragma unroll
            for (int j = 0; j < 4; ++j) {
                acc[i][j] = __builtin_amdgcn_mfma_f32_16x16x32_f16(a0[i], b0[j], acc[i][j], 0, 0, 0);
                acc[i][j] = __builtin_amdgcn_mfma_f32_16x16x32_f16(a1[i], b1[j], acc[i][j], 0, 0, 0);
            }
        __builtin_amdgcn_s_setprio(0);

        // Counted wait: tile t+1 must be landed; stage(t+2)'s 6 loads may remain.
        if (t < NT - 2)       asm volatile("s_waitcnt vmcnt(6)" ::: "memory");
        else if (t == NT - 2) asm volatile("s_waitcnt vmcnt(0)" ::: "memory");
        if (t < NT - 1) __builtin_amdgcn_s_barrier();

        if (++sC == 3) sC = 0;
        if (++sS == 3) sS = 0;
    }
#undef STAGE
#undef GL

    // Epilogue: bias + activation, f16 store. C/D: row=(lane>>4)*4+r, col=lane&15.
    #pragma unroll
    for (int j = 0; j < 4; ++j) {
        const int n = tileN + wc * 64 + j * 16 + l15;
        const float bn = bias[n];
        const bool is_tanh = (n < 1024);
        #pragma unroll
        for (int i = 0; i < 4; ++i) {
            const int mb = tileM + wr * 64 + i * 16 + hi * 4;
            #pragma unroll
            for (int r = 0; r < 4; ++r) {
                float v = acc[i][j][r] + bn;
                G[(size_t)(mb + r) * N_DIM + n] = (_Float16)(is_tanh ? tanhf(v) : sigmoid_f(v));
            }
        }
    }
}

// ---------------- chunked scan ----------------
__global__ void k_scan1(const _Float16* __restrict__ G,
                        float* __restrict__ sumA, float* __restrict__ sumH) {
    const int gid   = blockIdx.x;          // 0..1023
    const int dblk  = gid & 3;
    const int chunk = (gid >> 2) & 63;
    const int b     = gid >> 8;
    const int d     = dblk * 256 + threadIdx.x;

    const _Float16* base = G + (size_t)(b * S_LEN + chunk * CLEN) * N_DIM;
    float A = 1.0f, H = 0.0f;
    #pragma unroll 4
    for (int s = 0; s < CLEN; ++s) {
        float g0 = (float)base[(size_t)s * N_DIM + d];
        float g1 = (float)base[(size_t)s * N_DIM + 1024 + d];
        float a  = 1.0f - g1;
        float kv = g0 * g1;
        H = fmaf(a, H, kv);
        A *= a;
    }
    const int cidx = (b * NCHUNK + chunk) * 1024 + d;
    sumA[cidx] = A;
    sumH[cidx] = H;
}

__global__ void k_scan2(const float* __restrict__ sumA, const float* __restrict__ sumH,
                        float* __restrict__ pref) {
    const int c = blockIdx.x * blockDim.x + threadIdx.x;  // 0..4095
    const int b = c >> 10;
    const int d = c & 1023;
    float h = 0.0f;
    #pragma unroll 8
    for (int chunk = 0; chunk < NCHUNK; ++chunk) {
        const int idx = (b * NCHUNK + chunk) * 1024 + d;
        pref[idx] = h;
        h = fmaf(sumA[idx], h, sumH[idx]);
    }
}

__global__ void k_scan3(const _Float16* __restrict__ G,
                        const float* __restrict__ pref,
                        float* __restrict__ out) {
    const int gid   = blockIdx.x;
    const int dblk  = gid & 3;
    const int chunk = (gid >> 2) & 63;
    const int b     = gid >> 8;
    const int d     = dblk * 256 + threadIdx.x;

    const _Float16* base = G + (size_t)(b * S_LEN + chunk * CLEN) * N_DIM;
    float h = pref[(b * NCHUNK + chunk) * 1024 + d];
    #pragma unroll 4
    for (int s = 0; s < CLEN; ++s) {
        float g0 = (float)base[(size_t)s * N_DIM + d];
        float g1 = (float)base[(size_t)s * N_DIM + 1024 + d];
        float g2 = (float)base[(size_t)s * N_DIM + 2048 + d];
        float a  = 1.0f - g1;
        float kv = g0 * g1;
        h = fmaf(a, h, kv);
        out[(size_t)(b * S_LEN + chunk * CLEN + s) * 1024 + d] = tanhf(h) * g2;
    }
}

extern "C" void kernel_launch(void* const* d_in, const int* in_sizes, int n_in,
                              void* d_out, int out_size, void* d_ws, size_t ws_size,
                              hipStream_t stream) {
    const float* x = (const float*)d_in[0];
    const float* W = (const float*)d_in[1];
    const float* b = (const float*)d_in[2];
    float* out = (float*)d_out;

    char* ws = (char*)d_ws;
    _Float16* xb = (_Float16*)ws;                               // 32 MB
    _Float16* Wt = (_Float16*)(ws + 33554432);                  // 6 MB
    _Float16* G  = (_Float16*)(ws + 33554432 + 6291456);        // 96 MB
    float* sumA  = (float*)(ws + 140509184);
    float* sumH  = sumA + 4096 * NCHUNK;
    float* pref  = sumH + 4096 * NCHUNK;

    k_cast_x<<<16384, 256, 0, stream>>>(x, xb);
    k_cast_w<<<768,   256, 0, stream>>>(W, Wt);
    k_gemm <<<1536, 512, 3 * SLOT_E * sizeof(_Float16), stream>>>(xb, Wt, b, G);
    k_scan1<<<1024, 256, 0, stream>>>(G, sumA, sumH);
    k_scan2<<<16,   256, 0, stream>>>(sumA, sumH, pref);
    k_scan3<<<1024, 256, 0, stream>>>(G, pref, out);
    (void)in_sizes; (void)n_in; (void)out_size; (void)ws_size;
}

// Round 3
// 219.355 us; speedup vs baseline: 1.0681x; 1.0512x over previous
//
#include <hip/hip_runtime.h>
#include <hip/hip_bf16.h>
#include <cmath>

typedef _Float16 half8 __attribute__((ext_vector_type(8)));
typedef _Float16 half4 __attribute__((ext_vector_type(4)));
typedef float f32x4 __attribute__((ext_vector_type(4)));

// Geometry: B=4, S=4096, D=1024, D_H=1024 -> M=16384, K=1024, N=3072
#define M_DIM 16384
#define K_DIM 1024
#define N_DIM 3072
#define S_LEN 4096
#define NCHUNK 64
#define CLEN 64

// GEMM tiling: 256x256 tile, BK=64, 8 waves (2M x 4N), per-wave 128x64.
// LDS: 2 buffers x (A 256x64 + B 256x64) f16 = 128 KB.
#define BUF_E 32768    // elems per buffer (64KB)
#define B_OFF 16384    // B region offset within buffer (elems)

__device__ __forceinline__ float sigmoid_f(float x) {
    return 1.0f / (1.0f + __expf(-x));
}

// ---------------- cast kernels ----------------
__global__ void k_cast_x(const float* __restrict__ x, _Float16* __restrict__ xb) {
    int i = blockIdx.x * blockDim.x + threadIdx.x;
    float4 v = reinterpret_cast<const float4*>(x)[i];
    half4 h;
    h.x = (_Float16)v.x; h.y = (_Float16)v.y;
    h.z = (_Float16)v.z; h.w = (_Float16)v.w;
    reinterpret_cast<half4*>(xb)[i] = h;
}

__global__ void k_cast_w(const float* __restrict__ W, _Float16* __restrict__ Wt) {
    __shared__ float t[64][65];
    const int k0 = (blockIdx.x / 48) * 64;
    const int n0 = (blockIdx.x % 48) * 64;
    const int c  = threadIdx.x & 63;
    const int r0 = threadIdx.x >> 6;
    #pragma unroll
    for (int i = 0; i < 16; ++i) {
        int r = r0 + i * 4;
        t[r][c] = W[(size_t)(k0 + r) * N_DIM + n0 + c];
    }
    __syncthreads();
    #pragma unroll
    for (int i = 0; i < 16; ++i) {
        int r = r0 + i * 4;
        Wt[(size_t)(n0 + r) * K_DIM + k0 + c] = (_Float16)t[c][r];
    }
}

// ---------------- 8-phase GEMM + activation epilogue ----------------
__global__ __launch_bounds__(512, 2) void k_gemm(
    const _Float16* __restrict__ A,
    const _Float16* __restrict__ Bt,
    const float* __restrict__ bias,
    _Float16* __restrict__ G)
{
    extern __shared__ _Float16 lds[];   // 128 KB

    const int tid  = threadIdx.x;
    const int lane = tid & 63;
    const int wid  = tid >> 6;     // 0..7
    const int wr   = wid >> 2;     // 0..1 (M half, 128 rows)
    const int wc   = wid & 3;      // 0..3 (N quarter, 64 cols)

    // XCD swizzle: 768 blocks, 768 % 8 == 0
    const int bid   = blockIdx.x;
    const int wg    = (bid & 7) * 96 + (bid >> 3);
    const int tileM = (wg / 12) * 256;
    const int tileN = (wg % 12) * 256;

    // Staging: dest linear (global_load_lds adds lane*16B), source col pre-swizzled.
    const int l3   = lane >> 3;
    const int c8   = lane & 7;
    const int scol = ((c8 ^ l3) << 3);
    const _Float16* gA = A  + (size_t)(tileM + wid * 8 + l3) * K_DIM + scol;
    const _Float16* gB = Bt + (size_t)(tileN + wid * 8 + l3) * K_DIM + scol;
    _Float16* const sA = lds + wid * 512;           // + bufe + half*8192 (+4096)
    _Float16* const sB = lds + B_OFF + wid * 512;

    // Fragment reads: logical col-group read at group ^ (row&7); row&7 == l15&7.
    const int l15 = lane & 15;
    const int hi  = lane >> 4;
    const int swz = (l15 & 7) << 3;
    const int o0  = (hi * 8)      ^ swz;
    const int o1  = (32 + hi * 8) ^ swz;
    const _Float16* arow = lds + (wr * 128 + l15) * 64;          // + bufe + mh*4096 + m*1024
    const _Float16* brow = lds + B_OFF + (wc * 64 + l15) * 64;   // + bufe + nh*2048 + n*1024

    f32x4 acc[8][4] = {};
    half8 a[4][2], b[4][2];

#define GL(SRC, DST) __builtin_amdgcn_global_load_lds( \
        (const __attribute__((address_space(1))) void*)(SRC), \
        (__attribute__((address_space(3))) void*)(DST), 16, 0, 0)

#define STAGE_A(kt, half, bufe) do { \
        const _Float16* g_ = gA + (size_t)(kt) * 64 + (size_t)((half) * 128) * K_DIM; \
        GL(g_,                       sA + (bufe) + (half) * 8192);        \
        GL(g_ + (size_t)64 * K_DIM,  sA + (bufe) + (half) * 8192 + 4096); \
    } while (0)

#define STAGE_B(kt, half, bufe) do { \
        const _Float16* g_ = gB + (size_t)(kt) * 64 + (size_t)((half) * 128) * K_DIM; \
        GL(g_,                       sB + (bufe) + (half) * 8192);        \
        GL(g_ + (size_t)64 * K_DIM,  sB + (bufe) + (half) * 8192 + 4096); \
    } while (0)

#define RD_A(bufe, mh) do { const _Float16* p_ = arow + (bufe) + (mh) * 4096; \
        a[0][0] = *(const half8*)(p_ + o0);        a[0][1] = *(const half8*)(p_ + o1); \
        a[1][0] = *(const half8*)(p_ + 1024 + o0); a[1][1] = *(const half8*)(p_ + 1024 + o1); \
        a[2][0] = *(const half8*)(p_ + 2048 + o0); a[2][1] = *(const half8*)(p_ + 2048 + o1); \
        a[3][0] = *(const half8*)(p_ + 3072 + o0); a[3][1] = *(const half8*)(p_ + 3072 + o1); \
    } while (0)

#define RD_B(bufe, nh) do { const _Float16* p_ = brow + (bufe) + (nh) * 2048; \
        b[(nh)*2+0][0] = *(const half8*)(p_ + o0);        b[(nh)*2+0][1] = *(const half8*)(p_ + o1); \
        b[(nh)*2+1][0] = *(const half8*)(p_ + 1024 + o0); b[(nh)*2+1][1] = *(const half8*)(p_ + 1024 + o1); \
    } while (0)

#define MFMA_Q(mh, nh) do { \
        __builtin_amdgcn_s_setprio(1); \
        _Pragma("unroll") \
        for (int m_ = 0; m_ < 4; ++m_) { \
            _Pragma("unroll") \
            for (int n_ = 0; n_ < 2; ++n_) { \
                acc[(mh)*4+m_][(nh)*2+n_] = __builtin_amdgcn_mfma_f32_16x16x32_f16( \
                    a[m_][0], b[(nh)*2+n_][0], acc[(mh)*4+m_][(nh)*2+n_], 0, 0, 0); \
                acc[(mh)*4+m_][(nh)*2+n_] = __builtin_amdgcn_mfma_f32_16x16x32_f16( \
                    a[m_][1], b[(nh)*2+n_][1], acc[(mh)*4+m_][(nh)*2+n_], 0, 0, 0); \
            } } \
        __builtin_amdgcn_s_setprio(0); \
    } while (0)

#define BAR() do { __builtin_amdgcn_s_barrier(); asm volatile("" ::: "memory"); } while (0)
#define VM4() asm volatile("s_waitcnt vmcnt(4)" ::: "memory")
#define VM0() asm volatile("s_waitcnt vmcnt(0)" ::: "memory")

    // Prologue: tile0 complete + B-lo(1), A-lo(1) in flight.
    STAGE_B(0, 0, 0); STAGE_B(0, 1, 0);
    STAGE_A(0, 0, 0); STAGE_A(0, 1, 0);
    STAGE_B(1, 0, BUF_E); STAGE_A(1, 0, BUF_E);
    VM4();   // tile0's 4 halves landed; 2 halves of tile1 outstanding
    BAR();

    #pragma unroll 1
    for (int it = 0; it < 8; ++it) {
        const int kt0 = 2 * it;
        // ---- K-tile kt0 (buffer 0) ----
        // P1
        RD_A(0, 0); RD_B(0, 0);
        STAGE_B(kt0 + 1, 1, BUF_E);
        BAR(); MFMA_Q(0, 0); BAR();
        // P2
        RD_B(0, 1);
        STAGE_A(kt0 + 1, 1, BUF_E);
        BAR(); MFMA_Q(0, 1); BAR();
        // P3
        RD_A(0, 1);
        if (it < 7) STAGE_B(kt0 + 2, 0, 0);
        BAR(); MFMA_Q(1, 0); BAR();
        // P4
        if (it < 7) { STAGE_B(kt0 + 2, 1, 0); VM4(); } else { VM0(); }
        BAR(); MFMA_Q(1, 1); BAR();
        // ---- K-tile kt0+1 (buffer 1) ----
        // P5
        RD_A(BUF_E, 0); RD_B(BUF_E, 0);
        if (it < 7) STAGE_A(kt0 + 2, 0, 0);
        BAR(); MFMA_Q(0, 0); BAR();
        // P6
        RD_B(BUF_E, 1);
        if (it < 7) STAGE_A(kt0 + 2, 1, 0);
        BAR(); MFMA_Q(0, 1); BAR();
        // P7
        RD_A(BUF_E, 1);
        if (it < 7) STAGE_B(kt0 + 3, 0, BUF_E);
        BAR(); MFMA_Q(1, 0); BAR();
        // P8
        if (it < 7) { STAGE_A(kt0 + 3, 0, BUF_E); VM4(); }
        BAR(); MFMA_Q(1, 1); BAR();
    }

#undef STAGE_A
#undef STAGE_B
#undef RD_A
#undef RD_B
#undef MFMA_Q
#undef GL

    // Epilogue: bias + activation, f16 store. C/D: row=(lane>>4)*4+r, col=lane&15.
    #pragma unroll
    for (int j = 0; j < 4; ++j) {
        const int n = tileN + wc * 64 + j * 16 + l15;
        const float bn = bias[n];
        const bool is_tanh = (n < 1024);
        #pragma unroll
        for (int i = 0; i < 8; ++i) {
            const int mb = tileM + wr * 128 + i * 16 + hi * 4;
            #pragma unroll
            for (int r = 0; r < 4; ++r) {
                float v = acc[i][j][r] + bn;
                G[(size_t)(mb + r) * N_DIM + n] = (_Float16)(is_tanh ? tanhf(v) : sigmoid_f(v));
            }
        }
    }
}

// ---------------- chunked scan ----------------
__global__ void k_scan1(const _Float16* __restrict__ G,
                        float* __restrict__ sumA, float* __restrict__ sumH) {
    const int gid   = blockIdx.x;
    const int dblk  = gid & 3;
    const int chunk = (gid >> 2) & 63;
    const int b     = gid >> 8;
    const int d     = dblk * 256 + threadIdx.x;

    const _Float16* base = G + (size_t)(b * S_LEN + chunk * CLEN) * N_DIM;
    float A = 1.0f, H = 0.0f;
    #pragma unroll 4
    for (int s = 0; s < CLEN; ++s) {
        float g0 = (float)base[(size_t)s * N_DIM + d];
        float g1 = (float)base[(size_t)s * N_DIM + 1024 + d];
        float a  = 1.0f - g1;
        float kv = g0 * g1;
        H = fmaf(a, H, kv);
        A *= a;
    }
    const int cidx = (b * NCHUNK + chunk) * 1024 + d;
    sumA[cidx] = A;
    sumH[cidx] = H;
}

__global__ void k_scan2(const float* __restrict__ sumA, const float* __restrict__ sumH,
                        float* __restrict__ pref) {
    const int c = blockIdx.x * blockDim.x + threadIdx.x;
    const int b = c >> 10;
    const int d = c & 1023;
    float h = 0.0f;
    #pragma unroll 8
    for (int chunk = 0; chunk < NCHUNK; ++chunk) {
        const int idx = (b * NCHUNK + chunk) * 1024 + d;
        pref[idx] = h;
        h = fmaf(sumA[idx], h, sumH[idx]);
    }
}

__global__ void k_scan3(const _Float16* __restrict__ G,
                        const float* __restrict__ pref,
                        float* __restrict__ out) {
    const int gid   = blockIdx.x;
    const int dblk  = gid & 3;
    const int chunk = (gid >> 2) & 63;
    const int b     = gid >> 8;
    const int d     = dblk * 256 + threadIdx.x;

    const _Float16* base = G + (size_t)(b * S_LEN + chunk * CLEN) * N_DIM;
    float h = pref[(b * NCHUNK + chunk) * 1024 + d];
    #pragma unroll 4
    for (int s = 0; s < CLEN; ++s) {
        float g0 = (float)base[(size_t)s * N_DIM + d];
        float g1 = (float)base[(size_t)s * N_DIM + 1024 + d];
        float g2 = (float)base[(size_t)s * N_DIM + 2048 + d];
        float a  = 1.0f - g1;
        float kv = g0 * g1;
        h = fmaf(a, h, kv);
        out[(size_t)(b * S_LEN + chunk * CLEN + s) * 1024 + d] = tanhf(h) * g2;
    }
}

extern "C" void kernel_launch(void* const* d_in, const int* in_sizes, int n_in,
                              void* d_out, int out_size, void* d_ws, size_t ws_size,
                              hipStream_t stream) {
    const float* x = (const float*)d_in[0];
    const float* W = (const float*)d_in[1];
    const float* b = (const float*)d_in[2];
    float* out = (float*)d_out;

    char* ws = (char*)d_ws;
    _Float16* xb = (_Float16*)ws;                               // 32 MB
    _Float16* Wt = (_Float16*)(ws + 33554432);                  // 6 MB
    _Float16* G  = (_Float16*)(ws + 33554432 + 6291456);        // 96 MB
    float* sumA  = (float*)(ws + 140509184);
    float* sumH  = sumA + 4096 * NCHUNK;
    float* pref  = sumH + 4096 * NCHUNK;

    k_cast_x<<<16384, 256, 0, stream>>>(x, xb);
    k_cast_w<<<768,   256, 0, stream>>>(W, Wt);
    k_gemm <<<768, 512, 131072, stream>>>(xb, Wt, b, G);
    k_scan1<<<1024, 256, 0, stream>>>(G, sumA, sumH);
    k_scan2<<<16,   256, 0, stream>>>(sumA, sumH, pref);
    k_scan3<<<1024, 256, 0, stream>>>(G, pref, out);
    (void)in_sizes; (void)n_in; (void)out_size; (void)ws_size;
}

// Round 4
// 193.741 us; speedup vs baseline: 1.2093x; 1.1322x over previous
//
#include <hip/hip_runtime.h>
#include <hip/hip_bf16.h>
#include <cmath>

typedef _Float16 half8 __attribute__((ext_vector_type(8)));
typedef _Float16 half4 __attribute__((ext_vector_type(4)));
typedef float f32x4 __attribute__((ext_vector_type(4)));

// Geometry: B=4, S=4096, D=1024, D_H=1024 -> M=16384, K=1024, N=3072
#define M_DIM 16384
#define K_DIM 1024
#define N_DIM 3072
#define S_LEN 4096
#define NCHUNK 64
#define CLEN 64

// GEMM tiling: 256x256 tile, BK=64, 8 waves (2M x 4N), per-wave 128x64.
#define BUF_E 32768    // elems per LDS buffer (64KB)
#define B_OFF 16384    // B region offset within buffer (elems)

__device__ __forceinline__ float fast_sigmoid(float x) {
    return __builtin_amdgcn_rcpf(1.0f + __expf(-x));
}
__device__ __forceinline__ float fast_tanh(float x) {
    float t = __expf(-2.0f * __builtin_fabsf(x));
    float y = (1.0f - t) * __builtin_amdgcn_rcpf(1.0f + t);
    return __builtin_copysignf(y, x);
}

// ---------------- cast kernels ----------------
__global__ void k_cast_x(const float* __restrict__ x, _Float16* __restrict__ xb) {
    int i = blockIdx.x * blockDim.x + threadIdx.x;
    float4 v = reinterpret_cast<const float4*>(x)[i];
    half4 h;
    h.x = (_Float16)v.x; h.y = (_Float16)v.y;
    h.z = (_Float16)v.z; h.w = (_Float16)v.w;
    reinterpret_cast<half4*>(xb)[i] = h;
}

__global__ void k_cast_w(const float* __restrict__ W, _Float16* __restrict__ Wt) {
    __shared__ float t[64][65];
    const int k0 = (blockIdx.x / 48) * 64;
    const int n0 = (blockIdx.x % 48) * 64;
    const int c  = threadIdx.x & 63;
    const int r0 = threadIdx.x >> 6;
    #pragma unroll
    for (int i = 0; i < 16; ++i) {
        int r = r0 + i * 4;
        t[r][c] = W[(size_t)(k0 + r) * N_DIM + n0 + c];
    }
    __syncthreads();
    #pragma unroll
    for (int i = 0; i < 16; ++i) {
        int r = r0 + i * 4;
        Wt[(size_t)(n0 + r) * K_DIM + k0 + c] = (_Float16)t[c][r];
    }
}

// ---------------- 8-phase GEMM + activation epilogue ----------------
__global__ __launch_bounds__(512, 2) void k_gemm(
    const _Float16* __restrict__ A,
    const _Float16* __restrict__ Bt,
    const float* __restrict__ bias,
    _Float16* __restrict__ G)
{
    extern __shared__ _Float16 lds[];   // 128 KB

    const int tid  = threadIdx.x;
    const int lane = tid & 63;
    const int wid  = tid >> 6;
    const int wr   = wid >> 2;     // 0..1 (M half, 128 rows)
    const int wc   = wid & 3;      // 0..3 (N quarter, 64 cols)

    const int bid   = blockIdx.x;
    const int wg    = (bid & 7) * 96 + (bid >> 3);   // 768 % 8 == 0
    const int tileM = (wg / 12) * 256;
    const int tileN = (wg % 12) * 256;

    // Staging: LDS dest linear; global source column pre-swizzled (rule #21).
    const int l3   = lane >> 3;
    const int c8   = lane & 7;
    const int scol = ((c8 ^ l3) << 3);
    const _Float16* gA = A  + (size_t)(tileM + wid * 8 + l3) * K_DIM + scol;
    const _Float16* gB = Bt + (size_t)(tileN + wid * 8 + l3) * K_DIM + scol;
    _Float16* const sA = lds + wid * 512;
    _Float16* const sB = lds + B_OFF + wid * 512;

    // Fragment reads: col-group ^ (row&7); row&7 == l15&7.
    const int l15 = lane & 15;
    const int hi  = lane >> 4;
    const int swz = (l15 & 7) << 3;
    const int o0  = (hi * 8)      ^ swz;
    const int o1  = (32 + hi * 8) ^ swz;
    const _Float16* arow = lds + (wr * 128 + l15) * 64;
    const _Float16* brow = lds + B_OFF + (wc * 64 + l15) * 64;

    f32x4 acc[8][4] = {};
    half8 a[4][2], b[4][2];

#define GL(SRC, DST) __builtin_amdgcn_global_load_lds( \
        (const __attribute__((address_space(1))) void*)(SRC), \
        (__attribute__((address_space(3))) void*)(DST), 16, 0, 0)

#define STAGE_A(kt, half, bufe) do { \
        const _Float16* g_ = gA + (size_t)(kt) * 64 + (size_t)((half) * 128) * K_DIM; \
        GL(g_,                       sA + (bufe) + (half) * 8192);        \
        GL(g_ + (size_t)64 * K_DIM,  sA + (bufe) + (half) * 8192 + 4096); \
    } while (0)

#define STAGE_B(kt, half, bufe) do { \
        const _Float16* g_ = gB + (size_t)(kt) * 64 + (size_t)((half) * 128) * K_DIM; \
        GL(g_,                       sB + (bufe) + (half) * 8192);        \
        GL(g_ + (size_t)64 * K_DIM,  sB + (bufe) + (half) * 8192 + 4096); \
    } while (0)

#define RD_A(bufe, mh) do { const _Float16* p_ = arow + (bufe) + (mh) * 4096; \
        a[0][0] = *(const half8*)(p_ + o0);        a[0][1] = *(const half8*)(p_ + o1); \
        a[1][0] = *(const half8*)(p_ + 1024 + o0); a[1][1] = *(const half8*)(p_ + 1024 + o1); \
        a[2][0] = *(const half8*)(p_ + 2048 + o0); a[2][1] = *(const half8*)(p_ + 2048 + o1); \
        a[3][0] = *(const half8*)(p_ + 3072 + o0); a[3][1] = *(const half8*)(p_ + 3072 + o1); \
    } while (0)

#define RD_B(bufe, nh) do { const _Float16* p_ = brow + (bufe) + (nh) * 2048; \
        b[(nh)*2+0][0] = *(const half8*)(p_ + o0);        b[(nh)*2+0][1] = *(const half8*)(p_ + o1); \
        b[(nh)*2+1][0] = *(const half8*)(p_ + 1024 + o0); b[(nh)*2+1][1] = *(const half8*)(p_ + 1024 + o1); \
    } while (0)

// MFMA cluster: k0 group (8 independent) then k1 group.
#define MFMA_Q(mh, nh) do { \
        __builtin_amdgcn_s_setprio(1); \
        _Pragma("unroll") \
        for (int m_ = 0; m_ < 4; ++m_) { \
            acc[(mh)*4+m_][(nh)*2+0] = __builtin_amdgcn_mfma_f32_16x16x32_f16( \
                a[m_][0], b[(nh)*2+0][0], acc[(mh)*4+m_][(nh)*2+0], 0, 0, 0); \
            acc[(mh)*4+m_][(nh)*2+1] = __builtin_amdgcn_mfma_f32_16x16x32_f16( \
                a[m_][0], b[(nh)*2+1][0], acc[(mh)*4+m_][(nh)*2+1], 0, 0, 0); } \
        _Pragma("unroll") \
        for (int m_ = 0; m_ < 4; ++m_) { \
            acc[(mh)*4+m_][(nh)*2+0] = __builtin_amdgcn_mfma_f32_16x16x32_f16( \
                a[m_][1], b[(nh)*2+0][1], acc[(mh)*4+m_][(nh)*2+0], 0, 0, 0); \
            acc[(mh)*4+m_][(nh)*2+1] = __builtin_amdgcn_mfma_f32_16x16x32_f16( \
                a[m_][1], b[(nh)*2+1][1], acc[(mh)*4+m_][(nh)*2+1], 0, 0, 0); } \
        __builtin_amdgcn_s_setprio(0); \
    } while (0)

#define SCHED0() __builtin_amdgcn_sched_barrier(0)
// mid-phase: pin reads/stage before barrier; drain LDS; pin MFMA region start
#define PHASE_MID() do { SCHED0(); __builtin_amdgcn_s_barrier(); \
        asm volatile("s_waitcnt lgkmcnt(0)" ::: "memory"); SCHED0(); } while (0)
// end-phase: pin MFMA region end; barrier; compiler fence for next phase's reads
#define PHASE_END() do { SCHED0(); __builtin_amdgcn_s_barrier(); \
        asm volatile("" ::: "memory"); } while (0)
#define LGKM8() asm volatile("s_waitcnt lgkmcnt(8)" ::: "memory")
#define VM4()   asm volatile("s_waitcnt vmcnt(4)" ::: "memory")
#define VM0()   asm volatile("s_waitcnt vmcnt(0)" ::: "memory")

    // Prologue: tile0 complete; B-lo(1), A-lo(1) in flight.
    STAGE_B(0, 0, 0); STAGE_B(0, 1, 0);
    STAGE_A(0, 0, 0); STAGE_A(0, 1, 0);
    STAGE_B(1, 0, BUF_E); STAGE_A(1, 0, BUF_E);
    VM4();
    __builtin_amdgcn_s_barrier();
    asm volatile("" ::: "memory");

    #pragma unroll 1
    for (int it = 0; it < 8; ++it) {
        const int kt0 = 2 * it;
        // ---- K-tile kt0 (buffer 0) ----
        // P1
        RD_A(0, 0); RD_B(0, 0);
        STAGE_B(kt0 + 1, 1, BUF_E);
        LGKM8();
        PHASE_MID(); MFMA_Q(0, 0); PHASE_END();
        // P2
        RD_B(0, 1);
        STAGE_A(kt0 + 1, 1, BUF_E);
        PHASE_MID(); MFMA_Q(0, 1); PHASE_END();
        // P3
        RD_A(0, 1);
        if (it < 7) STAGE_B(kt0 + 2, 0, 0);
        PHASE_MID(); MFMA_Q(1, 0); PHASE_END();
        // P4
        if (it < 7) { STAGE_B(kt0 + 2, 1, 0); VM4(); } else { VM0(); }
        PHASE_MID(); MFMA_Q(1, 1); PHASE_END();
        // ---- K-tile kt0+1 (buffer 1) ----
        // P5
        RD_A(BUF_E, 0); RD_B(BUF_E, 0);
        if (it < 7) STAGE_A(kt0 + 2, 0, 0);
        LGKM8();
        PHASE_MID(); MFMA_Q(0, 0); PHASE_END();
        // P6
        RD_B(BUF_E, 1);
        if (it < 7) STAGE_A(kt0 + 2, 1, 0);
        PHASE_MID(); MFMA_Q(0, 1); PHASE_END();
        // P7
        RD_A(BUF_E, 1);
        if (it < 7) STAGE_B(kt0 + 3, 0, BUF_E);
        PHASE_MID(); MFMA_Q(1, 0); PHASE_END();
        // P8
        if (it < 7) { STAGE_A(kt0 + 3, 0, BUF_E); VM4(); }
        PHASE_MID(); MFMA_Q(1, 1); PHASE_END();
    }

#undef STAGE_A
#undef STAGE_B
#undef RD_A
#undef RD_B
#undef MFMA_Q
#undef GL

    // Epilogue: bias + activation, f16 store. C/D: row=(lane>>4)*4+r, col=lane&15.
    #pragma unroll
    for (int j = 0; j < 4; ++j) {
        const int n = tileN + wc * 64 + j * 16 + l15;
        const float bn = bias[n];
        const bool is_tanh = (n < 1024);
        #pragma unroll
        for (int i = 0; i < 8; ++i) {
            const int mb = tileM + wr * 128 + i * 16 + hi * 4;
            #pragma unroll
            for (int r = 0; r < 4; ++r) {
                float v = acc[i][j][r] + bn;
                G[(size_t)(mb + r) * N_DIM + n] =
                    (_Float16)(is_tanh ? fast_tanh(v) : fast_sigmoid(v));
            }
        }
    }
}

// ---------------- chunked scan (vectorized: 4 channels/thread) ----------------
// Level 1: grid 256 = (b,chunk); 256 threads; d0 = tid*4.
__global__ void k_scan1(const _Float16* __restrict__ G,
                        float* __restrict__ sumA, float* __restrict__ sumH) {
    const int chunk = blockIdx.x & 63;
    const int b     = blockIdx.x >> 6;
    const int d0    = threadIdx.x * 4;

    const _Float16* base = G + (size_t)(b * S_LEN + chunk * CLEN) * N_DIM;
    float A[4], H[4];
    #pragma unroll
    for (int j = 0; j < 4; ++j) { A[j] = 1.0f; H[j] = 0.0f; }
    #pragma unroll 4
    for (int s = 0; s < CLEN; ++s) {
        half4 v0 = *(const half4*)(base + (size_t)s * N_DIM + d0);
        half4 v1 = *(const half4*)(base + (size_t)s * N_DIM + 1024 + d0);
        #pragma unroll
        for (int j = 0; j < 4; ++j) {
            float g1 = (float)v1[j];
            float a  = 1.0f - g1;
            H[j] = fmaf(a, H[j], (float)v0[j] * g1);
            A[j] *= a;
        }
    }
    const int cidx = (b * NCHUNK + chunk) * 1024 + d0;
    *(float4*)(sumA + cidx) = make_float4(A[0], A[1], A[2], A[3]);
    *(float4*)(sumH + cidx) = make_float4(H[0], H[1], H[2], H[3]);
}

// Level 2: serial over 64 chunk summaries per channel.
__global__ void k_scan2(const float* __restrict__ sumA, const float* __restrict__ sumH,
                        float* __restrict__ pref) {
    const int c = blockIdx.x * blockDim.x + threadIdx.x;
    const int b = c >> 10;
    const int d = c & 1023;
    float h = 0.0f;
    #pragma unroll 8
    for (int chunk = 0; chunk < NCHUNK; ++chunk) {
        const int idx = (b * NCHUNK + chunk) * 1024 + d;
        pref[idx] = h;
        h = fmaf(sumA[idx], h, sumH[idx]);
    }
}

// Level 3: re-scan with carry-in; out = tanh(h) * output_gate.
__global__ void k_scan3(const _Float16* __restrict__ G,
                        const float* __restrict__ pref,
                        float* __restrict__ out) {
    const int chunk = blockIdx.x & 63;
    const int b     = blockIdx.x >> 6;
    const int d0    = threadIdx.x * 4;

    const _Float16* base = G + (size_t)(b * S_LEN + chunk * CLEN) * N_DIM;
    const int cidx = (b * NCHUNK + chunk) * 1024 + d0;
    float h[4];
    #pragma unroll
    for (int j = 0; j < 4; ++j) h[j] = pref[cidx + j];

    #pragma unroll 2
    for (int s = 0; s < CLEN; ++s) {
        half4 v0 = *(const half4*)(base + (size_t)s * N_DIM + d0);
        half4 v1 = *(const half4*)(base + (size_t)s * N_DIM + 1024 + d0);
        half4 v2 = *(const half4*)(base + (size_t)s * N_DIM + 2048 + d0);
        float4 o;
        #pragma unroll
        for (int j = 0; j < 4; ++j) {
            float g1 = (float)v1[j];
            float a  = 1.0f - g1;
            h[j] = fmaf(a, h[j], (float)v0[j] * g1);
            float t = fast_tanh(h[j]) * (float)v2[j];
            ((float*)&o)[j] = t;
        }
        *(float4*)(out + (size_t)(b * S_LEN + chunk * CLEN + s) * 1024 + d0) = o;
    }
}

extern "C" void kernel_launch(void* const* d_in, const int* in_sizes, int n_in,
                              void* d_out, int out_size, void* d_ws, size_t ws_size,
                              hipStream_t stream) {
    const float* x = (const float*)d_in[0];
    const float* W = (const float*)d_in[1];
    const float* b = (const float*)d_in[2];
    float* out = (float*)d_out;

    char* ws = (char*)d_ws;
    _Float16* xb = (_Float16*)ws;                               // 32 MB
    _Float16* Wt = (_Float16*)(ws + 33554432);                  // 6 MB
    _Float16* G  = (_Float16*)(ws + 33554432 + 6291456);        // 96 MB
    float* sumA  = (float*)(ws + 140509184);
    float* sumH  = sumA + 4096 * NCHUNK;
    float* pref  = sumH + 4096 * NCHUNK;

    k_cast_x<<<16384, 256, 0, stream>>>(x, xb);
    k_cast_w<<<768,   256, 0, stream>>>(W, Wt);
    k_gemm <<<768, 512, 131072, stream>>>(xb, Wt, b, G);
    k_scan1<<<256, 256, 0, stream>>>(G, sumA, sumH);
    k_scan2<<<16,  256, 0, stream>>>(sumA, sumH, pref);
    k_scan3<<<256, 256, 0, stream>>>(G, pref, out);
    (void)in_sizes; (void)n_in; (void)out_size; (void)ws_size;
}